// Round 12
// baseline (101.031 us; speedup 1.0000x reference)
//
#include <hip/hip_runtime.h>
#include <hip/hip_bf16.h>
#include <cstdint>

#define HEADS 12

typedef __attribute__((ext_vector_type(8))) __bf16 bf16x8;
typedef __attribute__((ext_vector_type(4))) __bf16 bf16x4;
typedef __attribute__((ext_vector_type(4))) float f32x4;
typedef __attribute__((ext_vector_type(16))) float f32x16;

#define AS1 __attribute__((address_space(1)))
#define AS3 __attribute__((address_space(3)))

__device__ __forceinline__ void gload16(const void* src, void* lds) {
  __builtin_amdgcn_global_load_lds((AS1 void*)src, (AS3 void*)lds, 16, 0, 0);
}

__device__ __forceinline__ uint32_t cvtpk(float lo, float hi) {
  uint32_t r;
  asm("v_cvt_pk_bf16_f32 %0, %1, %2" : "=v"(r) : "v"(lo), "v"(hi));
  return r;
}

__device__ __forceinline__ float exp2_fast(float x) {
  float r;
  asm("v_exp_f32 %0, %1" : "=v"(r) : "v"(x));
  return r;
}

// ---------------- cast fp32 -> bf16: x (6291456) then r (3145728) ----------------
__global__ void k_cast2(const float* __restrict__ x, const float* __restrict__ r,
                        __bf16* __restrict__ xb, __bf16* __restrict__ rb) {
  int i = (blockIdx.x * 256 + threadIdx.x) * 4;
  const float* src;
  __bf16* dst;
  int off;
  if (i < 6291456) { src = x; dst = xb; off = i; }
  else             { src = r; dst = rb; off = i - 6291456; }
  float4 v = *(const float4*)(src + off);
  bf16x4 o;
  o[0] = (__bf16)v.x; o[1] = (__bf16)v.y; o[2] = (__bf16)v.z; o[3] = (__bf16)v.w;
  *(bf16x4*)(dst + off) = o;
}

// ------------- transpose+cast all 3 weights: W[K][N] f32 -> Wt[N][K] bf16 (×scale) -------------
__global__ void k_twc3(const float* __restrict__ Wq, const float* __restrict__ Wkv,
                       const float* __restrict__ Wp, __bf16* __restrict__ wqt,
                       __bf16* __restrict__ wkvt, __bf16* __restrict__ wpt) {
  __shared__ float tile[32][33];
  const float* W; __bf16* Wt; int N; float scale;
  if (blockIdx.z == 0)      { W = Wq;  Wt = wqt;  N = 768;  scale = 0.18033688011112042f; }
  else if (blockIdx.z == 1) { W = Wkv; Wt = wkvt; N = 1536; scale = 1.0f; }
  else                      { W = Wp;  Wt = wpt;  N = 768;  scale = 1.0f; }
  int nt = blockIdx.x, kt = blockIdx.y;
  if (nt * 32 >= N) return;
  int c = threadIdx.x & 31, r0 = threadIdx.x >> 5;
#pragma unroll
  for (int i = 0; i < 4; ++i) {
    int r = r0 + i * 8;
    tile[r][c] = W[(size_t)(kt * 32 + r) * N + nt * 32 + c];
  }
  __syncthreads();
#pragma unroll
  for (int i = 0; i < 4; ++i) {
    int r = r0 + i * 8;
    Wt[(size_t)(nt * 32 + r) * 768 + kt * 32 + c] = (__bf16)(tile[c][r] * scale);
  }
}

// ---------------- fused Q-proj + KV-proj GEMM (768 blocks, flat id) ----------------
__global__ __launch_bounds__(256, 2) void k_gemm12(
    const __bf16* __restrict__ xb, const __bf16* __restrict__ rb,
    const __bf16* __restrict__ wqt, const __bf16* __restrict__ wkvt,
    __bf16* __restrict__ qb, __bf16* __restrict__ kbp, __bf16* __restrict__ vbp) {
  __shared__ __align__(16) char ldsA[2][16384];
  __shared__ __align__(16) char ldsB[2][16384];
  const int tid = threadIdx.x;
  const int ln = tid & 63;
  const int w = tid >> 6;
  int id = blockIdx.x;
  id = (id & 7) * 96 + (id >> 3);  // XCD chunking (768 % 8 == 0)
  const __bf16* A; const __bf16* Bt; int bm0, bn0; bool qpart;
  if (id < 384) { A = xb; Bt = wqt;  bm0 = (id / 6) * 128;  bn0 = (id % 6) * 128;  qpart = true; }
  else { int i2 = id - 384; A = rb; Bt = wkvt; bm0 = (i2 / 12) * 128; bn0 = (i2 % 12) * 128; qpart = false; }
  const int wm0 = (w >> 1) * 64, wn0 = (w & 1) * 64;

  auto stage = [&](char* lds, const __bf16* G, int row0, int k0) {
    const char* gb = (const char*)(G + (size_t)row0 * 768 + k0);
#pragma unroll
    for (int c = 0; c < 4; ++c) {
      int off = c * 4096 + tid * 16;
      int row = off >> 7;
      int s = ((off >> 4) & 7) ^ (row & 7);
      gload16(gb + (size_t)row * 1536 + (s << 4), lds + c * 4096 + (w << 10));
    }
  };

  f32x4 acc[4][4] = {};
  stage(ldsA[0], A, bm0, 0);
  stage(ldsB[0], Bt, bn0, 0);
  __syncthreads();
  for (int kt = 0; kt < 12; ++kt) {
    const char* bufA = ldsA[kt & 1];
    const char* bufB = ldsB[kt & 1];
    if (kt + 1 < 12) {
      stage(ldsA[(kt + 1) & 1], A, bm0, (kt + 1) << 6);
      stage(ldsB[(kt + 1) & 1], Bt, bn0, (kt + 1) << 6);
    }
    bf16x8 af[2][4], bf[2][4];
#pragma unroll
    for (int kk = 0; kk < 2; ++kk)
#pragma unroll
      for (int mt = 0; mt < 4; ++mt) {
        int row = wm0 + mt * 16 + (ln & 15);
        af[kk][mt] = *(const bf16x8*)(bufA + row * 128 + (((kk * 4 + (ln >> 4)) ^ (row & 7)) << 4));
      }
#pragma unroll
    for (int kk = 0; kk < 2; ++kk)
#pragma unroll
      for (int nt = 0; nt < 4; ++nt) {
        int row = wn0 + nt * 16 + (ln & 15);
        bf[kk][nt] = *(const bf16x8*)(bufB + row * 128 + (((kk * 4 + (ln >> 4)) ^ (row & 7)) << 4));
      }
    __builtin_amdgcn_s_setprio(1);
#pragma unroll
    for (int kk = 0; kk < 2; ++kk)
#pragma unroll
      for (int mt = 0; mt < 4; ++mt)
#pragma unroll
        for (int nt = 0; nt < 4; ++nt)
          acc[mt][nt] = __builtin_amdgcn_mfma_f32_16x16x32_bf16(af[kk][mt], bf[kk][nt], acc[mt][nt], 0, 0, 0);
    __builtin_amdgcn_s_setprio(0);
    __syncthreads();
  }

  // ---- LDS-staged epilogue (32KB tile in ldsA) ----
  char* ldsT = &ldsA[0][0];
  const bool vpart = (!qpart) && (bn0 >= 768);
  if (!vpart) {
#pragma unroll
    for (int mt = 0; mt < 4; ++mt)
#pragma unroll
      for (int nt = 0; nt < 4; ++nt)
#pragma unroll
        for (int jj = 0; jj < 4; ++jj) {
          int rowl = wm0 + mt * 16 + ((ln >> 4) << 2) + jj;
          int colb = (wn0 + nt * 16 + (ln & 15)) * 2;
          *(__bf16*)(ldsT + rowl * 256 + (colb ^ ((rowl & 7) << 4))) = (__bf16)acc[mt][nt][jj];
        }
  } else {
#pragma unroll
    for (int mt = 0; mt < 4; ++mt)
#pragma unroll
      for (int nt = 0; nt < 4; ++nt)
#pragma unroll
        for (int jj = 0; jj < 4; ++jj) {
          int dloc = wn0 + nt * 16 + (ln & 15);
          int kvb = (wm0 + mt * 16 + ((ln >> 4) << 2) + jj) * 2;
          *(__bf16*)(ldsT + dloc * 256 + (kvb ^ ((dloc & 7) << 4))) = (__bf16)acc[mt][nt][jj];
        }
  }
  __syncthreads();

  if (qpart) {
#pragma unroll
    for (int it = 0; it < 8; ++it) {
      int rowl = it * 16 + (tid >> 4);
      int colb = (tid & 15) * 16;
      bf16x8 v = *(const bf16x8*)(ldsT + rowl * 256 + (colb ^ ((rowl & 7) << 4)));
      *(bf16x8*)(qb + (size_t)(bm0 + rowl) * 768 + bn0 + (tid & 15) * 8) = v;
    }
  } else if (!vpart) {
    const int bb = bm0 >> 10, kvb0 = (bm0 & 1023) >> 5, hh0 = bn0 >> 6;
#pragma unroll
    for (int it = 0; it < 8; ++it) {
      int hh = it >> 2, t32 = it & 3;
      int dc = tid >> 5, kvl = tid & 31;
      int rowl = t32 * 32 + kvl;
      int colb = hh * 128 + (dc >> 1) * 32 + (dc & 1) * 16;
      bf16x8 v = *(const bf16x8*)(ldsT + rowl * 256 + (colb ^ ((rowl & 7) << 4)));
      *(bf16x8*)(kbp + ((size_t)(bb * 12 + hh0 + hh) * 32 + kvb0 + t32) * 2048 + tid * 8) = v;
    }
  } else {
    const int bb = bm0 >> 10, kvb0 = (bm0 & 1023) >> 5, hh0 = (bn0 - 768) >> 6;
#pragma unroll
    for (int it = 0; it < 8; ++it) {
      int hh = it >> 2, t32 = it & 3;
      int d = ((tid >> 7) << 5) + (tid & 31);
      int kvl8 = (((tid >> 6) & 1) << 4) + (((tid >> 5) & 1) << 3);
      int dloc = hh * 64 + d;
      int kvb = (t32 * 32 + kvl8) * 2;
      bf16x8 v = *(const bf16x8*)(ldsT + dloc * 256 + (kvb ^ ((dloc & 7) << 4)));
      *(bf16x8*)(vbp + ((size_t)(bb * 12 + hh0 + hh) * 32 + kvb0 + t32) * 2048 + tid * 8) = v;
    }
  }
}

// ---------------- out-proj GEMM: C[M][N] f32 = A @ Bt^T + bias ----------------
__global__ __launch_bounds__(256, 2) void k_gemmP(
    const __bf16* __restrict__ A, const __bf16* __restrict__ Bt,
    float* __restrict__ C, const float* __restrict__ bias) {
  __shared__ __align__(16) char ldsA[2][16384];
  __shared__ __align__(16) char ldsB[2][16384];
  const int tid = threadIdx.x;
  const int ln = tid & 63;
  const int w = tid >> 6;
  int bid = blockIdx.y * 6 + blockIdx.x;
  bid = (bid & 7) * 48 + (bid >> 3);  // 384 % 8 == 0
  const int bm0 = (bid / 6) * 128, bn0 = (bid % 6) * 128;
  const int wm0 = (w >> 1) * 64, wn0 = (w & 1) * 64;

  auto stage = [&](char* lds, const __bf16* G, int row0, int k0) {
    const char* gb = (const char*)(G + (size_t)row0 * 768 + k0);
#pragma unroll
    for (int c = 0; c < 4; ++c) {
      int off = c * 4096 + tid * 16;
      int row = off >> 7;
      int s = ((off >> 4) & 7) ^ (row & 7);
      gload16(gb + (size_t)row * 1536 + (s << 4), lds + c * 4096 + (w << 10));
    }
  };

  f32x4 acc[4][4] = {};
  stage(ldsA[0], A, bm0, 0);
  stage(ldsB[0], Bt, bn0, 0);
  __syncthreads();
  for (int kt = 0; kt < 12; ++kt) {
    const char* bufA = ldsA[kt & 1];
    const char* bufB = ldsB[kt & 1];
    if (kt + 1 < 12) {
      stage(ldsA[(kt + 1) & 1], A, bm0, (kt + 1) << 6);
      stage(ldsB[(kt + 1) & 1], Bt, bn0, (kt + 1) << 6);
    }
    bf16x8 af[2][4], bf[2][4];
#pragma unroll
    for (int kk = 0; kk < 2; ++kk)
#pragma unroll
      for (int mt = 0; mt < 4; ++mt) {
        int row = wm0 + mt * 16 + (ln & 15);
        af[kk][mt] = *(const bf16x8*)(bufA + row * 128 + (((kk * 4 + (ln >> 4)) ^ (row & 7)) << 4));
      }
#pragma unroll
    for (int kk = 0; kk < 2; ++kk)
#pragma unroll
      for (int nt = 0; nt < 4; ++nt) {
        int row = wn0 + nt * 16 + (ln & 15);
        bf[kk][nt] = *(const bf16x8*)(bufB + row * 128 + (((kk * 4 + (ln >> 4)) ^ (row & 7)) << 4));
      }
    __builtin_amdgcn_s_setprio(1);
#pragma unroll
    for (int kk = 0; kk < 2; ++kk)
#pragma unroll
      for (int mt = 0; mt < 4; ++mt)
#pragma unroll
        for (int nt = 0; nt < 4; ++nt)
          acc[mt][nt] = __builtin_amdgcn_mfma_f32_16x16x32_bf16(af[kk][mt], bf[kk][nt], acc[mt][nt], 0, 0, 0);
    __builtin_amdgcn_s_setprio(0);
    __syncthreads();
  }
#pragma unroll
  for (int mt = 0; mt < 4; ++mt) {
    int row = bm0 + wm0 + mt * 16 + ((ln >> 4) << 2);
#pragma unroll
    for (int nt = 0; nt < 4; ++nt) {
      int col = bn0 + wn0 + nt * 16 + (ln & 15);
      float bv = bias[col];
#pragma unroll
      for (int jj = 0; jj < 4; ++jj)
        C[(size_t)(row + jj) * 768 + col] = acc[mt][nt][jj] + bv;
    }
  }
}

// ---------------- flash attention: 2-wave blocks, T15 software pipeline ----------------
// 128 thr = 2 waves x 32q, grid 1536 (XCD-chunked), 6 blocks/CU. K via LDS
// (3-buffer, staged t+3 ahead). V global->reg, prefetched one full tile ahead.
// Per tile t: softmax(t)+PV(t) -> issue V(t+1)+stageK(t+3) -> sched_barrier ->
// QK(t+1) into the other S-buffer -> s_barrier.
// RAW induction: PV(t) waits all vf(t); vf(t) issued after stageK(t+1) -> FIFO
// vmcnt wait retires stage(t+1) before QK(t+1)'s ds_reads; sched_barrier(0)
// keeps those ds_reads below PV. WAR: stage(t+3) hits buf t%3, whose last
// reader QK(t) is separated by an s_barrier — including the PROLOGUE boundary
// (barrier added after QK(0); this was the R11 race).
__global__ __launch_bounds__(128, 3) void k_attn(
    const __bf16* __restrict__ q, const __bf16* __restrict__ kb,
    const __bf16* __restrict__ vb, __bf16* __restrict__ ao) {
  __shared__ __align__(16) char ldsK[3][8192];
  const int tid = threadIdx.x, ln = tid & 63;
  const int l5 = ln >> 5, l32 = ln & 31, w = tid >> 6;
  int id = blockIdx.x;
  id = (id & 7) * 192 + (id >> 3);  // XCD chunking (1536 % 8 == 0)
  const int qt = id & 31, bh = id >> 5;
  const int b = bh / HEADS, h = bh % HEADS;
  const int qrow = b * 2048 + qt * 64 + w * 32 + l32;

  const char* kbase = (const char*)kb + (size_t)bh * 131072;
  const __bf16* vbase = vb + (size_t)bh * 65536;
  const int vchunk = l5 * 256 + l32 * 8;

  auto stageK = [&](int t, int buf) {
#pragma unroll
    for (int c = 0; c < 4; ++c)
      gload16(kbase + (size_t)t * 8192 + c * 2048 + tid * 16, ldsK[buf] + c * 2048 + tid * 16);
  };

  bf16x8 qf[4];
#pragma unroll
  for (int s = 0; s < 4; ++s)
    qf[s] = *(const bf16x8*)(q + (size_t)qrow * 768 + h * 64 + 16 * s + 8 * l5);

  stageK(0, 0);
  stageK(1, 1);

  f32x16 accO[2] = {};
  float mrow = -1e30f, lrow = 0.f;
  bf16x8 vf[8];

  auto loadV = [&](int t) {
    const __bf16* vt = vbase + (size_t)(2 * t) * 2048 + vchunk;
#pragma unroll
    for (int nt = 0; nt < 2; ++nt)
#pragma unroll
      for (int dt = 0; dt < 2; ++dt)
#pragma unroll
        for (int ks = 0; ks < 2; ++ks)
          vf[nt * 4 + dt * 2 + ks] = *(const bf16x8*)(vt + nt * 2048 + (dt * 2 + ks) * 512);
  };

  auto QK = [&](int t, f32x16& s0, f32x16& s1) {
    const char* bufK = ldsK[t % 3];
    f32x16 r0 = {}, r1 = {};
    __builtin_amdgcn_s_setprio(1);
#pragma unroll
    for (int s = 0; s < 4; ++s) {
      bf16x8 kf0 = *(const bf16x8*)(bufK + (s * 2 + l5) * 512 + l32 * 16);
      r0 = __builtin_amdgcn_mfma_f32_32x32x16_bf16(kf0, qf[s], r0, 0, 0, 0);
      bf16x8 kf1 = *(const bf16x8*)(bufK + 4096 + (s * 2 + l5) * 512 + l32 * 16);
      r1 = __builtin_amdgcn_mfma_f32_32x32x16_bf16(kf1, qf[s], r1, 0, 0, 0);
    }
    __builtin_amdgcn_s_setprio(0);
    s0 = r0;
    s1 = r1;
  };

  auto SMPV = [&](f32x16& t0, f32x16& t1) {
    float lm = t0[0];
#pragma unroll
    for (int i = 0; i < 16; ++i) lm = fmaxf(lm, t0[i]);
#pragma unroll
    for (int i = 0; i < 16; ++i) lm = fmaxf(lm, t1[i]);
    if (!__all(lm <= mrow + 8.0f)) {
      float mx = fmaxf(lm, __shfl_xor(lm, 32, 64));
      float mn = fmaxf(mrow, mx);
      float corr = exp2_fast(mrow - mn);
      mrow = mn;
      lrow *= corr;
#pragma unroll
      for (int dt = 0; dt < 2; ++dt)
#pragma unroll
        for (int i = 0; i < 16; ++i) accO[dt][i] *= corr;
    }
    float ps = 0.f;
#pragma unroll
    for (int i = 0; i < 16; ++i) { float e = exp2_fast(t0[i] - mrow); t0[i] = e; ps += e; }
#pragma unroll
    for (int i = 0; i < 16; ++i) { float e = exp2_fast(t1[i] - mrow); t1[i] = e; ps += e; }
    lrow += ps;

    bf16x8 pk[2][2];
#pragma unroll
    for (int nt = 0; nt < 2; ++nt) {
      const f32x16& sv = nt ? t1 : t0;
      uint32_t c0[4], c1[4];
#pragma unroll
      for (int j = 0; j < 4; ++j) {
        c0[j] = cvtpk(sv[4 * j], sv[4 * j + 1]);
        c1[j] = cvtpk(sv[4 * j + 2], sv[4 * j + 3]);
      }
      uint32_t w00 = c0[0], w02 = c0[1];
      asm("v_permlane32_swap_b32 %0, %1" : "+v"(w00), "+v"(w02));
      uint32_t w01 = c1[0], w03 = c1[1];
      asm("v_permlane32_swap_b32 %0, %1" : "+v"(w01), "+v"(w03));
      uint32_t w10 = c0[2], w12 = c0[3];
      asm("v_permlane32_swap_b32 %0, %1" : "+v"(w10), "+v"(w12));
      uint32_t w11 = c1[2], w13 = c1[3];
      asm("v_permlane32_swap_b32 %0, %1" : "+v"(w11), "+v"(w13));
      union { uint32_t u[4]; bf16x8 v; } pk0, pk1;
      pk0.u[0] = w00; pk0.u[1] = w01; pk0.u[2] = w02; pk0.u[3] = w03;
      pk1.u[0] = w10; pk1.u[1] = w11; pk1.u[2] = w12; pk1.u[3] = w13;
      pk[nt][0] = pk0.v;
      pk[nt][1] = pk1.v;
    }

    __builtin_amdgcn_s_setprio(1);
#pragma unroll
    for (int nt = 0; nt < 2; ++nt)
#pragma unroll
      for (int ks = 0; ks < 2; ++ks) {
        accO[0] = __builtin_amdgcn_mfma_f32_32x32x16_bf16(vf[nt * 4 + ks], pk[nt][ks], accO[0], 0, 0, 0);
        accO[1] = __builtin_amdgcn_mfma_f32_32x32x16_bf16(vf[nt * 4 + 2 + ks], pk[nt][ks], accO[1], 0, 0, 0);
      }
    __builtin_amdgcn_s_setprio(0);
  };

  asm volatile("s_waitcnt vmcnt(0)" ::: "memory");
  __builtin_amdgcn_s_barrier();

  f32x16 sA0, sA1, sB0, sB1;
  loadV(0);
  stageK(2, 2);
  QK(0, sA0, sA1);              // ldsK[0] drained by prologue vmcnt(0)
  __builtin_amdgcn_s_barrier(); // RACE FIX: both waves done reading ldsK[0]
                                // before loop's stageK(3) overwrites it

#pragma unroll
  for (int i = 0; i < 8; ++i) {
    const int tA = 2 * i, tB = 2 * i + 1;
    // ---- tile tA ----
    SMPV(sA0, sA1);          // PV(tA) waits vf(tA) -> retires stage(tA+1)
    loadV(tA + 1);           // V for tB, covered by rest of this phase + barrier
    if (tA + 3 < 16) stageK(tA + 3, (tA + 3) % 3);
    __builtin_amdgcn_sched_barrier(0);
    QK(tB, sB0, sB1);
    __builtin_amdgcn_s_barrier();
    // ---- tile tB ----
    SMPV(sB0, sB1);          // PV(tB) waits vf(tB) -> retires stage(tB+1)
    if (tB < 15) {
      loadV(tB + 1);
      if (tB + 3 < 16) stageK(tB + 3, (tB + 3) % 3);
      __builtin_amdgcn_sched_barrier(0);
      QK(tB + 1, sA0, sA1);
    }
    __builtin_amdgcn_s_barrier();
  }

  // epilogue: lrow across l5 halves; O^T rows d = dt*32 + 8j + 4*l5 + (0..3)
  float l = lrow + __shfl_xor(lrow, 32, 64);
  float inv = 1.0f / l;
  size_t rowb = (size_t)qrow * 768 + h * 64;
#pragma unroll
  for (int dt = 0; dt < 2; ++dt)
#pragma unroll
    for (int j = 0; j < 4; ++j) {
      bf16x4 o;
#pragma unroll
      for (int i = 0; i < 4; ++i) o[i] = (__bf16)(accO[dt][4 * j + i] * inv);
      *(bf16x4*)(ao + rowb + dt * 32 + 8 * j + 4 * l5) = o;
    }
}

extern "C" void kernel_launch(void* const* d_in, const int* in_sizes, int n_in,
                              void* d_out, int out_size, void* d_ws, size_t ws_size,
                              hipStream_t stream) {
  const float* x = (const float*)d_in[0];
  const float* r = (const float*)d_in[1];
  const float* Wq = (const float*)d_in[2];
  const float* Wkv = (const float*)d_in[3];
  const float* Wp = (const float*)d_in[4];
  const float* bp = (const float*)d_in[5];

  char* ws = (char*)d_ws;
  __bf16* xb  = (__bf16*)ws; ws += (size_t)6291456 * 2;  // x bf16 (8192x768)
  __bf16* rb  = (__bf16*)ws; ws += (size_t)3145728 * 2;  // r bf16 (4096x768)
  __bf16* wqt = (__bf16*)ws; ws += (size_t)589824 * 2;   // W_q^T * SCALE*log2e
  __bf16* wkvt= (__bf16*)ws; ws += (size_t)1179648 * 2;  // W_kv^T (1536x768)
  __bf16* wpt = (__bf16*)ws; ws += (size_t)589824 * 2;   // W_proj^T (768x768)
  __bf16* qb  = (__bf16*)ws; ws += (size_t)6291456 * 2;  // q (8192x768), pre-scaled
  __bf16* kbk = (__bf16*)ws; ws += (size_t)3145728 * 2;  // K blocked (48 bh x 32 t x 4KB)
  __bf16* vbk = (__bf16*)ws; ws += (size_t)3145728 * 2;  // V blocked (48 bh x 32 t x 4KB)
  __bf16* ao  = (__bf16*)ws;                              // attn out (8192x768)

  k_cast2<<<9216, 256, 0, stream>>>(x, r, xb, rb);
  k_twc3<<<dim3(48, 24, 3), 256, 0, stream>>>(Wq, Wkv, Wp, wqt, wkvt, wpt);
  k_gemm12<<<768, 256, 0, stream>>>(xb, rb, wqt, wkvt, qb, kbk, vbk);
  k_attn<<<1536, 128, 0, stream>>>(qb, kbk, vbk, ao);
  k_gemmP<<<dim3(6, 64), 256, 0, stream>>>(ao, wpt, (float*)d_out, bp);
}

// Round 13
// 97.255 us; speedup vs baseline: 1.0388x; 1.0388x over previous
//
#include <hip/hip_runtime.h>
#include <hip/hip_bf16.h>
#include <cstdint>

#define HEADS 12

typedef __attribute__((ext_vector_type(8))) __bf16 bf16x8;
typedef __attribute__((ext_vector_type(4))) __bf16 bf16x4;
typedef __attribute__((ext_vector_type(4))) float f32x4;
typedef __attribute__((ext_vector_type(16))) float f32x16;

#define AS1 __attribute__((address_space(1)))
#define AS3 __attribute__((address_space(3)))

__device__ __forceinline__ void gload16(const void* src, void* lds) {
  __builtin_amdgcn_global_load_lds((AS1 void*)src, (AS3 void*)lds, 16, 0, 0);
}

__device__ __forceinline__ uint32_t cvtpk(float lo, float hi) {
  uint32_t r;
  asm("v_cvt_pk_bf16_f32 %0, %1, %2" : "=v"(r) : "v"(lo), "v"(hi));
  return r;
}

__device__ __forceinline__ float exp2_fast(float x) {
  float r;
  asm("v_exp_f32 %0, %1" : "=v"(r) : "v"(x));
  return r;
}

// ---------------- fused prep: cast x,r -> bf16 AND transpose+cast 3 weights ----------------
// blocks [0,9216): vectorized cast of x (6291456) then r (3145728).
// blocks [9216,12672): weight transpose, 1152 blocks per weight (48 x 24).
__global__ void k_prep(const float* __restrict__ x, const float* __restrict__ r,
                       const float* __restrict__ Wq, const float* __restrict__ Wkv,
                       const float* __restrict__ Wp,
                       __bf16* __restrict__ xb, __bf16* __restrict__ rb,
                       __bf16* __restrict__ wqt, __bf16* __restrict__ wkvt,
                       __bf16* __restrict__ wpt) {
  __shared__ float tile[32][33];
  const int bid = blockIdx.x, tid = threadIdx.x;
  if (bid < 9216) {
    int i = (bid * 256 + tid) * 4;
    const float* src;
    __bf16* dst;
    int off;
    if (i < 6291456) { src = x; dst = xb; off = i; }
    else             { src = r; dst = rb; off = i - 6291456; }
    float4 v = *(const float4*)(src + off);
    bf16x4 o;
    o[0] = (__bf16)v.x; o[1] = (__bf16)v.y; o[2] = (__bf16)v.z; o[3] = (__bf16)v.w;
    *(bf16x4*)(dst + off) = o;
    return;
  }
  int wb = bid - 9216;
  int z = wb / 1152, rem = wb % 1152;
  int nt = rem % 48, kt = rem / 48;
  const float* W; __bf16* Wt; int N; float scale;
  if (z == 0)      { W = Wq;  Wt = wqt;  N = 768;  scale = 0.18033688011112042f; }  // SCALE*log2e
  else if (z == 1) { W = Wkv; Wt = wkvt; N = 1536; scale = 1.0f; }
  else             { W = Wp;  Wt = wpt;  N = 768;  scale = 1.0f; }
  if (nt * 32 >= N) return;
  int c = tid & 31, r0 = tid >> 5;
#pragma unroll
  for (int i = 0; i < 4; ++i) {
    int rr = r0 + i * 8;
    tile[rr][c] = W[(size_t)(kt * 32 + rr) * N + nt * 32 + c];
  }
  __syncthreads();
#pragma unroll
  for (int i = 0; i < 4; ++i) {
    int rr = r0 + i * 8;
    Wt[(size_t)(nt * 32 + rr) * 768 + kt * 32 + c] = (__bf16)(tile[c][rr] * scale);
  }
}

// ---------------- fused Q-proj + KV-proj GEMM (768 blocks, flat id) ----------------
// id<384: qb[8192x768] = xb @ wqt^T (row-major).
// id>=384: K/V in MFMA-fragment-blocked layouts (attn-validated):
//   K block (bh,t32): elem = dc*256 + kvl*8 + (d&7), dc = ((d>>4)<<1)+((d>>3)&1)
//   V block (bh,t32): elem = (((d5*2+kv4)*2+kv3)*32 + (d&31))*8 + (kvl&7)
// Epilogue via LDS: coalesced 4KB-run global writes.
__global__ __launch_bounds__(256, 2) void k_gemm12(
    const __bf16* __restrict__ xb, const __bf16* __restrict__ rb,
    const __bf16* __restrict__ wqt, const __bf16* __restrict__ wkvt,
    __bf16* __restrict__ qb, __bf16* __restrict__ kbp, __bf16* __restrict__ vbp) {
  __shared__ __align__(16) char ldsA[2][16384];
  __shared__ __align__(16) char ldsB[2][16384];
  const int tid = threadIdx.x;
  const int ln = tid & 63;
  const int w = tid >> 6;
  int id = blockIdx.x;
  id = (id & 7) * 96 + (id >> 3);  // XCD chunking (768 % 8 == 0)
  const __bf16* A; const __bf16* Bt; int bm0, bn0; bool qpart;
  if (id < 384) { A = xb; Bt = wqt;  bm0 = (id / 6) * 128;  bn0 = (id % 6) * 128;  qpart = true; }
  else { int i2 = id - 384; A = rb; Bt = wkvt; bm0 = (i2 / 12) * 128; bn0 = (i2 % 12) * 128; qpart = false; }
  const int wm0 = (w >> 1) * 64, wn0 = (w & 1) * 64;

  auto stage = [&](char* lds, const __bf16* G, int row0, int k0) {
    const char* gb = (const char*)(G + (size_t)row0 * 768 + k0);
#pragma unroll
    for (int c = 0; c < 4; ++c) {
      int off = c * 4096 + tid * 16;
      int row = off >> 7;
      int s = ((off >> 4) & 7) ^ (row & 7);
      gload16(gb + (size_t)row * 1536 + (s << 4), lds + c * 4096 + (w << 10));
    }
  };

  f32x4 acc[4][4] = {};
  stage(ldsA[0], A, bm0, 0);
  stage(ldsB[0], Bt, bn0, 0);
  __syncthreads();
  for (int kt = 0; kt < 12; ++kt) {
    const char* bufA = ldsA[kt & 1];
    const char* bufB = ldsB[kt & 1];
    if (kt + 1 < 12) {
      stage(ldsA[(kt + 1) & 1], A, bm0, (kt + 1) << 6);
      stage(ldsB[(kt + 1) & 1], Bt, bn0, (kt + 1) << 6);
    }
    bf16x8 af[2][4], bf[2][4];
#pragma unroll
    for (int kk = 0; kk < 2; ++kk)
#pragma unroll
      for (int mt = 0; mt < 4; ++mt) {
        int row = wm0 + mt * 16 + (ln & 15);
        af[kk][mt] = *(const bf16x8*)(bufA + row * 128 + (((kk * 4 + (ln >> 4)) ^ (row & 7)) << 4));
      }
#pragma unroll
    for (int kk = 0; kk < 2; ++kk)
#pragma unroll
      for (int nt = 0; nt < 4; ++nt) {
        int row = wn0 + nt * 16 + (ln & 15);
        bf[kk][nt] = *(const bf16x8*)(bufB + row * 128 + (((kk * 4 + (ln >> 4)) ^ (row & 7)) << 4));
      }
    __builtin_amdgcn_s_setprio(1);
#pragma unroll
    for (int kk = 0; kk < 2; ++kk)
#pragma unroll
      for (int mt = 0; mt < 4; ++mt)
#pragma unroll
        for (int nt = 0; nt < 4; ++nt)
          acc[mt][nt] = __builtin_amdgcn_mfma_f32_16x16x32_bf16(af[kk][mt], bf[kk][nt], acc[mt][nt], 0, 0, 0);
    __builtin_amdgcn_s_setprio(0);
    __syncthreads();
  }

  // ---- LDS-staged epilogue (32KB tile in ldsA) ----
  char* ldsT = &ldsA[0][0];
  const bool vpart = (!qpart) && (bn0 >= 768);
  if (!vpart) {
#pragma unroll
    for (int mt = 0; mt < 4; ++mt)
#pragma unroll
      for (int nt = 0; nt < 4; ++nt)
#pragma unroll
        for (int jj = 0; jj < 4; ++jj) {
          int rowl = wm0 + mt * 16 + ((ln >> 4) << 2) + jj;
          int colb = (wn0 + nt * 16 + (ln & 15)) * 2;
          *(__bf16*)(ldsT + rowl * 256 + (colb ^ ((rowl & 7) << 4))) = (__bf16)acc[mt][nt][jj];
        }
  } else {
#pragma unroll
    for (int mt = 0; mt < 4; ++mt)
#pragma unroll
      for (int nt = 0; nt < 4; ++nt)
#pragma unroll
        for (int jj = 0; jj < 4; ++jj) {
          int dloc = wn0 + nt * 16 + (ln & 15);
          int kvb = (wm0 + mt * 16 + ((ln >> 4) << 2) + jj) * 2;
          *(__bf16*)(ldsT + dloc * 256 + (kvb ^ ((dloc & 7) << 4))) = (__bf16)acc[mt][nt][jj];
        }
  }
  __syncthreads();

  if (qpart) {
#pragma unroll
    for (int it = 0; it < 8; ++it) {
      int rowl = it * 16 + (tid >> 4);
      int colb = (tid & 15) * 16;
      bf16x8 v = *(const bf16x8*)(ldsT + rowl * 256 + (colb ^ ((rowl & 7) << 4)));
      *(bf16x8*)(qb + (size_t)(bm0 + rowl) * 768 + bn0 + (tid & 15) * 8) = v;
    }
  } else if (!vpart) {
    const int bb = bm0 >> 10, kvb0 = (bm0 & 1023) >> 5, hh0 = bn0 >> 6;
#pragma unroll
    for (int it = 0; it < 8; ++it) {
      int hh = it >> 2, t32 = it & 3;
      int dc = tid >> 5, kvl = tid & 31;
      int rowl = t32 * 32 + kvl;
      int colb = hh * 128 + (dc >> 1) * 32 + (dc & 1) * 16;
      bf16x8 v = *(const bf16x8*)(ldsT + rowl * 256 + (colb ^ ((rowl & 7) << 4)));
      *(bf16x8*)(kbp + ((size_t)(bb * 12 + hh0 + hh) * 32 + kvb0 + t32) * 2048 + tid * 8) = v;
    }
  } else {
    const int bb = bm0 >> 10, kvb0 = (bm0 & 1023) >> 5, hh0 = (bn0 - 768) >> 6;
#pragma unroll
    for (int it = 0; it < 8; ++it) {
      int hh = it >> 2, t32 = it & 3;
      int d = ((tid >> 7) << 5) + (tid & 31);
      int kvl8 = (((tid >> 6) & 1) << 4) + (((tid >> 5) & 1) << 3);
      int dloc = hh * 64 + d;
      int kvb = (t32 * 32 + kvl8) * 2;
      bf16x8 v = *(const bf16x8*)(ldsT + dloc * 256 + (kvb ^ ((dloc & 7) << 4)));
      *(bf16x8*)(vbp + ((size_t)(bb * 12 + hh0 + hh) * 32 + kvb0 + t32) * 2048 + tid * 8) = v;
    }
  }
}

// ---------------- out-proj GEMM: C[M][N] f32 = A @ Bt^T + bias ----------------
__global__ __launch_bounds__(256, 2) void k_gemmP(
    const __bf16* __restrict__ A, const __bf16* __restrict__ Bt,
    float* __restrict__ C, const float* __restrict__ bias) {
  __shared__ __align__(16) char ldsA[2][16384];
  __shared__ __align__(16) char ldsB[2][16384];
  const int tid = threadIdx.x;
  const int ln = tid & 63;
  const int w = tid >> 6;
  int bid = blockIdx.y * 6 + blockIdx.x;
  bid = (bid & 7) * 48 + (bid >> 3);  // 384 % 8 == 0
  const int bm0 = (bid / 6) * 128, bn0 = (bid % 6) * 128;
  const int wm0 = (w >> 1) * 64, wn0 = (w & 1) * 64;

  auto stage = [&](char* lds, const __bf16* G, int row0, int k0) {
    const char* gb = (const char*)(G + (size_t)row0 * 768 + k0);
#pragma unroll
    for (int c = 0; c < 4; ++c) {
      int off = c * 4096 + tid * 16;
      int row = off >> 7;
      int s = ((off >> 4) & 7) ^ (row & 7);
      gload16(gb + (size_t)row * 1536 + (s << 4), lds + c * 4096 + (w << 10));
    }
  };

  f32x4 acc[4][4] = {};
  stage(ldsA[0], A, bm0, 0);
  stage(ldsB[0], Bt, bn0, 0);
  __syncthreads();
  for (int kt = 0; kt < 12; ++kt) {
    const char* bufA = ldsA[kt & 1];
    const char* bufB = ldsB[kt & 1];
    if (kt + 1 < 12) {
      stage(ldsA[(kt + 1) & 1], A, bm0, (kt + 1) << 6);
      stage(ldsB[(kt + 1) & 1], Bt, bn0, (kt + 1) << 6);
    }
    bf16x8 af[2][4], bf[2][4];
#pragma unroll
    for (int kk = 0; kk < 2; ++kk)
#pragma unroll
      for (int mt = 0; mt < 4; ++mt) {
        int row = wm0 + mt * 16 + (ln & 15);
        af[kk][mt] = *(const bf16x8*)(bufA + row * 128 + (((kk * 4 + (ln >> 4)) ^ (row & 7)) << 4));
      }
#pragma unroll
    for (int kk = 0; kk < 2; ++kk)
#pragma unroll
      for (int nt = 0; nt < 4; ++nt) {
        int row = wn0 + nt * 16 + (ln & 15);
        bf[kk][nt] = *(const bf16x8*)(bufB + row * 128 + (((kk * 4 + (ln >> 4)) ^ (row & 7)) << 4));
      }
    __builtin_amdgcn_s_setprio(1);
#pragma unroll
    for (int kk = 0; kk < 2; ++kk)
#pragma unroll
      for (int mt = 0; mt < 4; ++mt)
#pragma unroll
        for (int nt = 0; nt < 4; ++nt)
          acc[mt][nt] = __builtin_amdgcn_mfma_f32_16x16x32_bf16(af[kk][mt], bf[kk][nt], acc[mt][nt], 0, 0, 0);
    __builtin_amdgcn_s_setprio(0);
    __syncthreads();
  }
#pragma unroll
  for (int mt = 0; mt < 4; ++mt) {
    int row = bm0 + wm0 + mt * 16 + ((ln >> 4) << 2);
#pragma unroll
    for (int nt = 0; nt < 4; ++nt) {
      int col = bn0 + wn0 + nt * 16 + (ln & 15);
      float bv = bias[col];
#pragma unroll
      for (int jj = 0; jj < 4; ++jj)
        C[(size_t)(row + jj) * 768 + col] = acc[mt][nt][jj] + bv;
    }
  }
}

// ---------------- flash attention: R8 structure, KVBLK=128 phases ----------------
// 4 waves x 32q, grid 768 (XCD-chunked), 3 blocks/CU. Outer phase stages 16KB
// (two 64-kv K tiles) via flat gload16 memcpy, 3-deep; two inner 64-kv sub-tiles
// between barriers (halves barrier count vs R8: 8 instead of 16). V global->reg
// (L2-resident blocked layout, coalesced 512B), issued at sub-tile top.
// RAW: PV(sub) waits vf, which was issued after stage(p+2) -> FIFO vmcnt retires
// all earlier staging before the end-of-phase barrier; QK(p) reads buf staged at
// phase p-2, retired by p-1's PV waits in every wave before its barrier.
// WAR: stage(p+2) writes buf (p+2)%3=(p-1)%3, last read by QK(p-1), separated
// by the end-of-phase-(p-1) barrier.
__global__ __launch_bounds__(256, 3) void k_attn(
    const __bf16* __restrict__ q, const __bf16* __restrict__ kb,
    const __bf16* __restrict__ vb, __bf16* __restrict__ ao) {
  __shared__ __align__(16) char ldsK[3][16384];
  const int tid = threadIdx.x, ln = tid & 63;
  const int l5 = ln >> 5, l32 = ln & 31, w = tid >> 6;
  int id = blockIdx.y * 16 + blockIdx.x;
  id = (id & 7) * 96 + (id >> 3);  // XCD chunking (768 % 8 == 0)
  const int qt = id & 15, bh = id >> 4;
  const int b = bh / HEADS, h = bh % HEADS;
  const int qrow = b * 2048 + qt * 128 + w * 32 + l32;

  const char* kbase = (const char*)kb + (size_t)bh * 131072;
  const __bf16* vbase = vb + (size_t)bh * 65536;
  const int vchunk = l5 * 256 + l32 * 8;

  auto stageKpair = [&](int p, int buf) {
#pragma unroll
    for (int c = 0; c < 4; ++c)
      gload16(kbase + (size_t)p * 16384 + c * 4096 + tid * 16, ldsK[buf] + c * 4096 + tid * 16);
  };

  bf16x8 qf[4];
#pragma unroll
  for (int s = 0; s < 4; ++s)
    qf[s] = *(const bf16x8*)(q + (size_t)qrow * 768 + h * 64 + 16 * s + 8 * l5);

  stageKpair(0, 0);
  stageKpair(1, 1);

  f32x16 accO[2] = {};
  float mrow = -1e30f, lrow = 0.f;

  asm volatile("s_waitcnt vmcnt(0)" ::: "memory");
  __builtin_amdgcn_s_barrier();

  for (int p = 0; p < 8; ++p) {
    const char* bufK = ldsK[p % 3];
    if (p < 6) stageKpair(p + 2, (p + 2) % 3);

#pragma unroll
    for (int sub = 0; sub < 2; ++sub) {
      const int t = 2 * p + sub;  // 64-kv tile index
      const char* bK = bufK + sub * 8192;

      // V fragments direct from global (blocked layout, coalesced)
      bf16x8 vf[2][2][2];
      {
        const __bf16* vt = vbase + (size_t)(2 * t) * 2048 + vchunk;
#pragma unroll
        for (int nt = 0; nt < 2; ++nt)
#pragma unroll
          for (int dt = 0; dt < 2; ++dt)
#pragma unroll
            for (int ks = 0; ks < 2; ++ks)
              vf[nt][dt][ks] = *(const bf16x8*)(vt + nt * 2048 + (dt * 2 + ks) * 512);
      }

      f32x16 s16[2] = {};
      __builtin_amdgcn_s_setprio(1);
#pragma unroll
      for (int s = 0; s < 4; ++s) {
        bf16x8 kf0 = *(const bf16x8*)(bK + (s * 2 + l5) * 512 + l32 * 16);
        s16[0] = __builtin_amdgcn_mfma_f32_32x32x16_bf16(kf0, qf[s], s16[0], 0, 0, 0);
        bf16x8 kf1 = *(const bf16x8*)(bK + 4096 + (s * 2 + l5) * 512 + l32 * 16);
        s16[1] = __builtin_amdgcn_mfma_f32_32x32x16_bf16(kf1, qf[s], s16[1], 0, 0, 0);
      }
      __builtin_amdgcn_s_setprio(0);

      float lm = s16[0][0];
#pragma unroll
      for (int nt = 0; nt < 2; ++nt)
#pragma unroll
        for (int i = 0; i < 16; ++i) lm = fmaxf(lm, s16[nt][i]);
      if (!__all(lm <= mrow + 8.0f)) {
        float mx = fmaxf(lm, __shfl_xor(lm, 32, 64));
        float mn = fmaxf(mrow, mx);
        float corr = exp2_fast(mrow - mn);
        mrow = mn;
        lrow *= corr;
#pragma unroll
        for (int dt = 0; dt < 2; ++dt)
#pragma unroll
          for (int i = 0; i < 16; ++i) accO[dt][i] *= corr;
      }
      float ps = 0.f;
#pragma unroll
      for (int nt = 0; nt < 2; ++nt)
#pragma unroll
        for (int i = 0; i < 16; ++i) {
          float e = exp2_fast(s16[nt][i] - mrow);
          s16[nt][i] = e;
          ps += e;
        }
      lrow += ps;

      bf16x8 pk[2][2];
#pragma unroll
      for (int nt = 0; nt < 2; ++nt) {
        uint32_t c0[4], c1[4];
#pragma unroll
        for (int j = 0; j < 4; ++j) {
          c0[j] = cvtpk(s16[nt][4 * j], s16[nt][4 * j + 1]);
          c1[j] = cvtpk(s16[nt][4 * j + 2], s16[nt][4 * j + 3]);
        }
        uint32_t w00 = c0[0], w02 = c0[1];
        asm("v_permlane32_swap_b32 %0, %1" : "+v"(w00), "+v"(w02));
        uint32_t w01 = c1[0], w03 = c1[1];
        asm("v_permlane32_swap_b32 %0, %1" : "+v"(w01), "+v"(w03));
        uint32_t w10 = c0[2], w12 = c0[3];
        asm("v_permlane32_swap_b32 %0, %1" : "+v"(w10), "+v"(w12));
        uint32_t w11 = c1[2], w13 = c1[3];
        asm("v_permlane32_swap_b32 %0, %1" : "+v"(w11), "+v"(w13));
        union { uint32_t u[4]; bf16x8 v; } pk0, pk1;
        pk0.u[0] = w00; pk0.u[1] = w01; pk0.u[2] = w02; pk0.u[3] = w03;
        pk1.u[0] = w10; pk1.u[1] = w11; pk1.u[2] = w12; pk1.u[3] = w13;
        pk[nt][0] = pk0.v;
        pk[nt][1] = pk1.v;
      }

      __builtin_amdgcn_s_setprio(1);
#pragma unroll
      for (int nt = 0; nt < 2; ++nt)
#pragma unroll
        for (int ks = 0; ks < 2; ++ks) {
          accO[0] = __builtin_amdgcn_mfma_f32_32x32x16_bf16(vf[nt][0][ks], pk[nt][ks], accO[0], 0, 0, 0);
          accO[1] = __builtin_amdgcn_mfma_f32_32x32x16_bf16(vf[nt][1][ks], pk[nt][ks], accO[1], 0, 0, 0);
        }
      __builtin_amdgcn_s_setprio(0);
    }

    __builtin_amdgcn_sched_barrier(0);
    __builtin_amdgcn_s_barrier();
  }

  // epilogue: lrow across l5 halves; O^T rows d = dt*32 + 8j + 4*l5 + (0..3)
  float l = lrow + __shfl_xor(lrow, 32, 64);
  float inv = 1.0f / l;
  size_t rowb = (size_t)qrow * 768 + h * 64;
#pragma unroll
  for (int dt = 0; dt < 2; ++dt)
#pragma unroll
    for (int j = 0; j < 4; ++j) {
      bf16x4 o;
#pragma unroll
      for (int i = 0; i < 4; ++i) o[i] = (__bf16)(accO[dt][4 * j + i] * inv);
      *(bf16x4*)(ao + rowb + dt * 32 + 8 * j + 4 * l5) = o;
    }
}

extern "C" void kernel_launch(void* const* d_in, const int* in_sizes, int n_in,
                              void* d_out, int out_size, void* d_ws, size_t ws_size,
                              hipStream_t stream) {
  const float* x = (const float*)d_in[0];
  const float* r = (const float*)d_in[1];
  const float* Wq = (const float*)d_in[2];
  const float* Wkv = (const float*)d_in[3];
  const float* Wp = (const float*)d_in[4];
  const float* bp = (const float*)d_in[5];

  char* ws = (char*)d_ws;
  __bf16* xb  = (__bf16*)ws; ws += (size_t)6291456 * 2;  // x bf16 (8192x768)
  __bf16* rb  = (__bf16*)ws; ws += (size_t)3145728 * 2;  // r bf16 (4096x768)
  __bf16* wqt = (__bf16*)ws; ws += (size_t)589824 * 2;   // W_q^T * SCALE*log2e
  __bf16* wkvt= (__bf16*)ws; ws += (size_t)1179648 * 2;  // W_kv^T (1536x768)
  __bf16* wpt = (__bf16*)ws; ws += (size_t)589824 * 2;   // W_proj^T (768x768)
  __bf16* qb  = (__bf16*)ws; ws += (size_t)6291456 * 2;  // q (8192x768), pre-scaled
  __bf16* kbk = (__bf16*)ws; ws += (size_t)3145728 * 2;  // K blocked (48 bh x 32 t x 4KB)
  __bf16* vbk = (__bf16*)ws; ws += (size_t)3145728 * 2;  // V blocked (48 bh x 32 t x 4KB)
  __bf16* ao  = (__bf16*)ws;                              // attn out (8192x768)

  k_prep<<<12672, 256, 0, stream>>>(x, r, Wq, Wkv, Wp, xb, rb, wqt, wkvt, wpt);
  k_gemm12<<<768, 256, 0, stream>>>(xb, rb, wqt, wkvt, qb, kbk, vbk);
  k_attn<<<dim3(16, 48), 256, 0, stream>>>(qb, kbk, vbk, ao);
  k_gemmP<<<dim3(6, 64), 256, 0, stream>>>(ao, wpt, (float*)d_out, bp);
}